// Round 1
// baseline (878.754 us; speedup 1.0000x reference)
//
#include <hip/hip_runtime.h>
#include <math.h>

#define BATCH 32
#define CI 8
#define CO 8
#define KCAP 4
#define DIN 16
#define DOUT 16
#define SS 32
#define HW (SS*SS)          // 1024
#define OC (CI*CO*DOUT)     // 1024
#define EPSF 1e-5f

// ---- workspace layout (float element offsets) ----
#define N_VOTES   (BATCH*OC*HW)            // 33,554,432
#define N_PLANE   (BATCH*CO*DOUT*HW)       // 4,194,304
#define OFF_VOTES 0
#define OFF_PMAX  (OFF_VOTES + N_VOTES)
#define OFF_PMEAN (OFF_PMAX + N_PLANE)
#define OFF_G     (OFF_PMEAN + N_PLANE)
#define OFF_CN    (OFF_G + N_PLANE)
#define OFF_STATS (OFF_CN + N_PLANE)
// stats region: bnsum[8], bnsq[8], lnsum[256], lnsq[256]
#define ST_BNSUM 0
#define ST_BNSQ  8
#define ST_LNSUM 16
#define ST_LNSQ  272
#define STATS_FLOATS 528

__device__ __forceinline__ void block_reduce_add2(float a, float b, float* da, float* db) {
    #pragma unroll
    for (int off = 32; off > 0; off >>= 1) {
        a += __shfl_down(a, off);
        b += __shfl_down(b, off);
    }
    __shared__ float sa[4], sb[4];
    int w = threadIdx.x >> 6;
    if ((threadIdx.x & 63) == 0) { sa[w] = a; sb[w] = b; }
    __syncthreads();
    if (threadIdx.x == 0) {
        atomicAdd(da, sa[0] + sa[1] + sa[2] + sa[3]);
        atomicAdd(db, sb[0] + sb[1] + sb[2] + sb[3]);
    }
}

// ---------------- Kernel A: conv2d (caps -> votes) ----------------
// block (16,16): each thread computes 2x2 pixels x 4 output channels.
// grid (256 ocq, 32 b)
__global__ __launch_bounds__(256) void conv2d_kernel(
        const float* __restrict__ caps, const float* __restrict__ Wt,
        const float* __restrict__ bt, float* __restrict__ votes)
{
    const int px = threadIdx.x;            // 0..15 -> v0 = 2*px
    const int py = threadIdx.y;            // 0..15 -> u0 = 2*py
    const int oc0 = blockIdx.x * 4;
    const int b = blockIdx.y;
    const int u0 = py * 2, v0 = px * 2;

    float acc[4][4];
    #pragma unroll
    for (int j = 0; j < 4; j++) {
        float bj = bt[oc0 + j];
        #pragma unroll
        for (int p = 0; p < 4; p++) acc[j][p] = bj;
    }

    const float* capb = caps + (size_t)b * DIN * HW;
    for (int din = 0; din < DIN; ++din) {
        const float* cp = capb + din * HW;
        float x[4][4];
        #pragma unroll
        for (int r = 0; r < 4; r++) {
            int ur = u0 - 1 + r;
            bool vu = (ur >= 0 && ur < SS);
            #pragma unroll
            for (int cx = 0; cx < 4; cx++) {
                int vcl = v0 - 1 + cx;
                bool ok = vu && (vcl >= 0 && vcl < SS);
                x[r][cx] = ok ? cp[ur * SS + vcl] : 0.f;
            }
        }
        #pragma unroll
        for (int j = 0; j < 4; j++) {
            const float* wp = Wt + ((size_t)(oc0 + j) * DIN + din) * 9;
            #pragma unroll
            for (int ku = 0; ku < 3; ku++) {
                #pragma unroll
                for (int kv = 0; kv < 3; kv++) {
                    float w = wp[ku * 3 + kv];
                    #pragma unroll
                    for (int r = 0; r < 2; r++)
                        #pragma unroll
                        for (int cx = 0; cx < 2; cx++)
                            acc[j][r * 2 + cx] += w * x[r + ku][cx + kv];
                }
            }
        }
    }
    #pragma unroll
    for (int j = 0; j < 4; j++) {
        float* vp = votes + ((size_t)(b * OC + oc0 + j)) * HW;
        #pragma unroll
        for (int r = 0; r < 2; r++) {
            float2 st = make_float2(acc[j][r * 2 + 0], acc[j][r * 2 + 1]);
            *reinterpret_cast<float2*>(vp + (u0 + r) * SS + v0) = st;
        }
    }
}

// ---------------- Kernel B: einsum + pool over m (votes -> pmax/pmean) -------
// grid 16384 blocks x 256: blk = ((b*CO+o)*DOUT+d)*4 + q ; thread = 1 pixel
__global__ __launch_bounds__(256) void pool_kernel(
        const float* __restrict__ votes, const float* __restrict__ Wv,
        const float* __restrict__ bv, float* __restrict__ pmax, float* __restrict__ pmean)
{
    int blk = blockIdx.x;
    int q = blk & 3, d = (blk >> 2) & 15, o = (blk >> 6) & 7, b = blk >> 9;
    int uv = q * 256 + threadIdx.x;

    const float* vp = votes + ((size_t)b * OC + o * DOUT + d) * HW + uv;
    float vc[CI];
    #pragma unroll
    for (int c = 0; c < CI; c++) vc[c] = vp[(size_t)c * (CO * DOUT * HW)];

    const float* wv = Wv + o * (KCAP * CI) * CI;   // [m][c]
    const float* bvo = bv + o * (KCAP * CI);
    float vmax = -INFINITY, vsum = 0.f;
    #pragma unroll
    for (int m = 0; m < KCAP * CI; m++) {
        float a = bvo[m];
        #pragma unroll
        for (int c = 0; c < CI; c++) a += wv[m * CI + c] * vc[c];
        vmax = fmaxf(vmax, a);
        vsum += a;
    }
    size_t oidx = ((size_t)((b * CO + o) * DOUT + d)) * HW + uv;
    pmax[oidx] = vmax;
    pmean[oidx] = vsum * (1.f / 32.f);
}

// ---------------- Kernel C: 3x3x3 gate conv + BN partial sums ----------------
__global__ __launch_bounds__(256) void gate_kernel(
        const float* __restrict__ pmax, const float* __restrict__ pmean,
        const float* __restrict__ Wsp, float* __restrict__ g, float* __restrict__ stats)
{
    int blk = blockIdx.x;
    int q = blk & 3, d = (blk >> 2) & 15, o = (blk >> 6) & 7, b = blk >> 9;
    int uv = q * 256 + threadIdx.x;
    int u = uv >> 5, v = uv & 31;

    const float* pmx = pmax + ((size_t)(b * CO + o) * DOUT) * HW;
    const float* pmn = pmean + ((size_t)(b * CO + o) * DOUT) * HW;
    float acc = 0.f;
    #pragma unroll
    for (int dd = -1; dd <= 1; dd++) {
        int dz = d + dd;
        bool okd = (dz >= 0 && dz < DOUT);
        #pragma unroll
        for (int du = -1; du <= 1; du++) {
            int uu = u + du;
            bool oku = okd && (uu >= 0 && uu < SS);
            #pragma unroll
            for (int dv = -1; dv <= 1; dv++) {
                int vv = v + dv;
                bool ok = oku && (vv >= 0 && vv < SS);
                if (ok) {
                    int idx = dz * HW + uu * SS + vv;
                    int widx = (dd + 1) * 9 + (du + 1) * 3 + (dv + 1);
                    acc += Wsp[widx] * pmx[idx] + Wsp[27 + widx] * pmn[idx];
                }
            }
        }
    }
    g[((size_t)(b * CO + o) * DOUT + d) * HW + uv] = acc;
    block_reduce_add2(acc, acc * acc, &stats[ST_BNSUM + o], &stats[ST_BNSQ + o]);
}

// ---------------- Kernel E1: gate apply + routing + LN partials --------------
__global__ __launch_bounds__(256) void route_kernel(
        const float* __restrict__ votes, const float* __restrict__ g,
        const float* __restrict__ Wv, const float* __restrict__ bv,
        const float* __restrict__ bn_gamma, const float* __restrict__ bn_beta,
        float* __restrict__ cn, float* __restrict__ stats)
{
    int blk = blockIdx.x;
    int q = blk & 3, d = (blk >> 2) & 15, o = (blk >> 6) & 7, b = blk >> 9;
    int uv = q * 256 + threadIdx.x;

    const float nbn = 1.f / (float)(BATCH * DOUT * HW);
    float mu = stats[ST_BNSUM + o] * nbn;
    float var = stats[ST_BNSQ + o] * nbn - mu * mu;
    float rstd = rsqrtf(var + EPSF);
    float gg = g[((size_t)(b * CO + o) * DOUT + d) * HW + uv];
    float gn = (gg - mu) * rstd * bn_gamma[0] + bn_beta[0];
    float f = 1.f + 1.f / (1.f + expf(-gn));

    const float* vp = votes + ((size_t)b * OC + o * DOUT + d) * HW + uv;
    float vc[CI];
    #pragma unroll
    for (int c = 0; c < CI; c++) vc[c] = vp[(size_t)c * (CO * DOUT * HW)];

    const float* wv = Wv + o * (KCAP * CI) * CI;
    const float* bvo = bv + o * (KCAP * CI);
    float val[KCAP * CI];
    #pragma unroll
    for (int m = 0; m < KCAP * CI; m++) {
        float a = bvo[m];
        #pragma unroll
        for (int c = 0; c < CI; c++) a += wv[m * CI + c] * vc[c];
        val[m] = a;
    }
    // per ci: mean/std over kc; softmax(-log std) == (1/std)/sum(1/std);
    // the (1+s) gate factor cancels inside the softmax.
    float wsum = 0.f, accm = 0.f;
    #pragma unroll
    for (int ci = 0; ci < CI; ci++) {
        float s1 = 0.f, s2 = 0.f;
        #pragma unroll
        for (int kc = 0; kc < KCAP; kc++) {
            float t = val[kc * CI + ci];
            s1 += t; s2 += t * t;
        }
        float mean = s1 * 0.25f;
        float v2 = fmaxf(s2 * 0.25f - mean * mean, 0.f);
        float r = rsqrtf(v2);
        wsum += r;
        accm += r * mean;
    }
    float cnv = f * accm / wsum;
    cn[((size_t)(b * CO + o) * DOUT + d) * HW + uv] = cnv;
    block_reduce_add2(cnv, cnv * cnv,
                      &stats[ST_LNSUM + b * CO + o], &stats[ST_LNSQ + b * CO + o]);
}

// ---------------- Kernel E2: LayerNorm + transpose-out -----------------------
// grid 1024 x 256 : blk = bo*4 + q4 ; bo = b*8+o
__global__ __launch_bounds__(256) void ln_kernel(
        const float* __restrict__ cn, const float* __restrict__ stats,
        const float* __restrict__ lng, const float* __restrict__ lnb,
        float* __restrict__ out)
{
    int blk = blockIdx.x;
    int bo = blk >> 2;
    int q4 = blk & 3;
    int b = bo >> 3, o = bo & 7;
    const float nln = 1.f / 16384.f;
    float mu = stats[ST_LNSUM + bo] * nln;
    float var = stats[ST_LNSQ + bo] * nln - mu * mu;
    float rstd = rsqrtf(var + EPSF);
    const float* src = cn + (size_t)bo * 16384;
    float* dst = out + ((size_t)(o * BATCH + b)) * 16384;
    #pragma unroll
    for (int i = 0; i < 16; i++) {
        int e = q4 * 4096 + i * 256 + threadIdx.x;
        float x = src[e];
        dst[e] = (x - mu) * rstd * lng[e] + lnb[e];
    }
}

extern "C" void kernel_launch(void* const* d_in, const int* in_sizes, int n_in,
                              void* d_out, int out_size, void* d_ws, size_t ws_size,
                              hipStream_t stream) {
    const float* caps = (const float*)d_in[0];
    const float* Wt   = (const float*)d_in[1];
    const float* bt   = (const float*)d_in[2];
    const float* Wv   = (const float*)d_in[3];
    const float* bv   = (const float*)d_in[4];
    const float* Wsp  = (const float*)d_in[5];
    const float* bng  = (const float*)d_in[6];
    const float* bnb  = (const float*)d_in[7];
    const float* lng  = (const float*)d_in[8];
    const float* lnb  = (const float*)d_in[9];
    float* ws = (float*)d_ws;
    float* votes = ws + OFF_VOTES;
    float* pmax  = ws + OFF_PMAX;
    float* pmean = ws + OFF_PMEAN;
    float* g     = ws + OFF_G;
    float* cn    = ws + OFF_CN;
    float* stats = ws + OFF_STATS;
    float* out = (float*)d_out;

    hipMemsetAsync(stats, 0, STATS_FLOATS * sizeof(float), stream);
    conv2d_kernel<<<dim3(256, 32), dim3(16, 16), 0, stream>>>(caps, Wt, bt, votes);
    pool_kernel<<<16384, 256, 0, stream>>>(votes, Wv, bv, pmax, pmean);
    gate_kernel<<<16384, 256, 0, stream>>>(pmax, pmean, Wsp, g, stats);
    route_kernel<<<16384, 256, 0, stream>>>(votes, g, Wv, bv, bng, bnb, cn, stats);
    ln_kernel<<<1024, 256, 0, stream>>>(cn, stats, lng, lnb, out);
}

// Round 4
// 441.917 us; speedup vs baseline: 1.9885x; 1.9885x over previous
//
#include <hip/hip_runtime.h>
#include <math.h>

#define BATCH 32
#define CI 8
#define CO 8
#define KCAP 4
#define DIN 16
#define DOUT 16
#define SS 32
#define HW (SS*SS)          // 1024
#define OC (CI*CO*DOUT)     // 1024
#define EPSF 1e-5f

// ---- workspace layout (float element offsets) ----
#define N_VOTES   (BATCH*OC*HW)            // 33,554,432
#define N_PLANE   (BATCH*CO*DOUT*HW)       // 4,194,304
#define OFF_VOTES 0
#define OFF_G     (OFF_VOTES + N_VOTES)
#define OFF_CN    (OFF_G + N_PLANE)
#define OFF_STATS (OFF_CN + N_PLANE)
#define ST_BNSUM 0
#define ST_BNSQ  8
#define ST_LNSUM 16
#define ST_LNSQ  272
#define STATS_FLOATS 528

__device__ __forceinline__ void wave_reduce_atomic2(float a, float b, float* da, float* db) {
    #pragma unroll
    for (int off = 32; off > 0; off >>= 1) {
        a += __shfl_down(a, off);
        b += __shfl_down(b, off);
    }
    if ((threadIdx.x & 63) == 0) {
        atomicAdd(da, a);
        atomicAdd(db, b);
    }
}

// ---------------- Kernel A: conv2d (caps -> votes), LDS-staged half-tiles ----
// grid (32, 32): blockIdx.x = ocg*2 + half (ocg 0..15), blockIdx.y = b.
// LDS: xs[16][18][36] = 41,472 B (< 64 KiB). Thread: 1 row x 2 cols x 8 oc.
__global__ __launch_bounds__(256) void conv2d_kernel(
        const float* __restrict__ caps, const float* __restrict__ Wt,
        const float* __restrict__ bt, float* __restrict__ votes)
{
    __shared__ float xs[DIN * 18 * 36];
    const int tid = threadIdx.x;
    const int half = blockIdx.x & 1;
    const int oc0 = (blockIdx.x >> 1) * 64;
    const int b = blockIdx.y;
    const int r0 = half * 16;            // first output row of this block

    // zero fill (halo rows/cols)
    for (int i = tid; i < DIN * 18 * 36; i += 256) xs[i] = 0.f;
    __syncthreads();
    // interior fill: DIN*18 rows x 8 float4 groups = 2304 vec4 loads
    const float* capb = caps + (size_t)b * DIN * HW;
    #pragma unroll
    for (int it = 0; it < 9; ++it) {
        const int idx = it * 256 + tid;          // 0..2303
        const int din = idx / 144;
        const int rem = idx - din * 144;
        const int row = rem >> 3;                // 0..17 (LDS row)
        const int c4 = rem & 7;                  // 0..7
        const int gr = r0 - 1 + row;             // global input row, -1..32
        if (gr >= 0 && gr < SS) {
            float4 ld = *reinterpret_cast<const float4*>(capb + din * HW + gr * SS + c4 * 4);
            float* dst = &xs[din * (18 * 36) + row * 36 + 1 + c4 * 4];
            dst[0] = ld.x; dst[1] = ld.y; dst[2] = ld.z; dst[3] = ld.w;
        }
    }
    __syncthreads();

    const int ul = tid >> 4;              // 0..15 local output row
    const int v0 = (tid & 15) * 2;        // output col 0,2,..30
    const int U = r0 + ul;                // global output row

    for (int chunk = 0; chunk < 8; ++chunk) {
        const int occ = oc0 + chunk * 8;
        float acc[8][2];
        #pragma unroll
        for (int j = 0; j < 8; j++) {
            float bj = bt[occ + j];
            acc[j][0] = bj; acc[j][1] = bj;
        }
        for (int din = 0; din < DIN; ++din) {
            // xs row = ul+ku covers input rows U-1..U+1; xs col = input col + 1
            float x[3][4];
            #pragma unroll
            for (int r = 0; r < 3; r++)
                #pragma unroll
                for (int c = 0; c < 4; c++)
                    x[r][c] = xs[din * (18 * 36) + (ul + r) * 36 + (v0 + c)];
            #pragma unroll
            for (int j = 0; j < 8; j++) {
                const float* wp = Wt + ((size_t)(occ + j) * DIN + din) * 9;  // uniform -> s_load
                #pragma unroll
                for (int ku = 0; ku < 3; ku++)
                    #pragma unroll
                    for (int kv = 0; kv < 3; kv++) {
                        float w = wp[ku * 3 + kv];
                        acc[j][0] += w * x[ku][kv];
                        acc[j][1] += w * x[ku][kv + 1];
                    }
            }
        }
        #pragma unroll
        for (int j = 0; j < 8; j++) {
            float2 st = make_float2(acc[j][0], acc[j][1]);
            *reinterpret_cast<float2*>(votes + ((size_t)b * OC + occ + j) * HW + U * SS + v0) = st;
        }
    }
}

// ------- Kernel B: fused einsum+pool+3x3x3 gate conv + BN partials -----------
// grid 1024: blk = b*32 + o*4 + slab. Block: 4 owned d-planes (6 with halo).
// LDS: 2 x 6 x 1024 x 4B = 49,152 B (< 64 KiB).
__global__ __launch_bounds__(256) void poolgate_kernel(
        const float* __restrict__ votes, const float* __restrict__ Wv,
        const float* __restrict__ bv, const float* __restrict__ Wsp,
        float* __restrict__ g, float* __restrict__ stats)
{
    __shared__ float pmx[6 * HW];
    __shared__ float pmn[6 * HW];
    const int tid = threadIdx.x;
    const int slab = blockIdx.x & 3;
    const int o = (blockIdx.x >> 2) & 7;
    const int b = blockIdx.x >> 5;
    const int d0 = slab * 4 - 1;          // global d of LDS plane 0

    const float* wv = Wv + (size_t)o * (KCAP * CI) * CI;  // uniform
    const float* bvo = bv + (size_t)o * (KCAP * CI);
    const int px0 = tid * 4;

    for (int p = 0; p < 6; ++p) {
        const int d = d0 + p;
        if (d >= 0 && d < DOUT) {
            const float* vpb = votes + ((size_t)b * OC + (size_t)o * DOUT + d) * HW + px0;
            float4 vc[CI];
            #pragma unroll
            for (int c = 0; c < CI; c++)
                vc[c] = *reinterpret_cast<const float4*>(vpb + (size_t)c * (CO * DOUT * HW));
            float4 mx = make_float4(-1e30f, -1e30f, -1e30f, -1e30f);
            float4 sm = make_float4(0.f, 0.f, 0.f, 0.f);
            #pragma unroll
            for (int m = 0; m < KCAP * CI; m++) {
                float bm = bvo[m];
                float4 a = make_float4(bm, bm, bm, bm);
                #pragma unroll
                for (int c = 0; c < CI; c++) {
                    float w = wv[m * CI + c];
                    a.x += w * vc[c].x; a.y += w * vc[c].y;
                    a.z += w * vc[c].z; a.w += w * vc[c].w;
                }
                mx.x = fmaxf(mx.x, a.x); mx.y = fmaxf(mx.y, a.y);
                mx.z = fmaxf(mx.z, a.z); mx.w = fmaxf(mx.w, a.w);
                sm.x += a.x; sm.y += a.y; sm.z += a.z; sm.w += a.w;
            }
            const float inv = 1.f / 32.f;
            *reinterpret_cast<float4*>(&pmx[p * HW + px0]) = mx;
            *reinterpret_cast<float4*>(&pmn[p * HW + px0]) =
                make_float4(sm.x * inv, sm.y * inv, sm.z * inv, sm.w * inv);
        } else {
            float4 z = make_float4(0.f, 0.f, 0.f, 0.f);
            *reinterpret_cast<float4*>(&pmx[p * HW + px0]) = z;
            *reinterpret_cast<float4*>(&pmn[p * HW + px0]) = z;
        }
    }
    __syncthreads();

    // stencil over LDS for owned planes p=1..4
    float bnsum = 0.f, bnsq = 0.f;
    for (int i = 0; i < 16; ++i) {
        const int idx = i * 256 + tid;       // 0..4095
        const int p = 1 + (idx >> 10);       // 1..4
        const int pix = idx & 1023;
        const int u = pix >> 5, v = pix & 31;
        float acc = 0.f;
        #pragma unroll
        for (int dd = -1; dd <= 1; dd++) {
            const int pp = p + dd;           // 0..5
            #pragma unroll
            for (int du = -1; du <= 1; du++) {
                const int uu = u + du;
                if (uu < 0 || uu >= SS) continue;
                #pragma unroll
                for (int dv = -1; dv <= 1; dv++) {
                    const int vv = v + dv;
                    if (vv < 0 || vv >= SS) continue;
                    const int widx = (dd + 1) * 9 + (du + 1) * 3 + (dv + 1);
                    const int lidx = pp * HW + uu * SS + vv;
                    acc += Wsp[widx] * pmx[lidx] + Wsp[27 + widx] * pmn[lidx];
                }
            }
        }
        const int d = d0 + p;
        g[(((size_t)b * CO + o) * DOUT + d) * HW + pix] = acc;
        bnsum += acc; bnsq += acc * acc;
    }
    wave_reduce_atomic2(bnsum, bnsq, &stats[ST_BNSUM + o], &stats[ST_BNSQ + o]);
}

// ---------------- Kernel C: gate apply + routing + LN partials ---------------
// grid 4096: blk = (b*8+o)*16 + d. Thread: 4 consecutive px (float4).
__global__ __launch_bounds__(256) void route_kernel(
        const float* __restrict__ votes, const float* __restrict__ g,
        const float* __restrict__ Wv, const float* __restrict__ bv,
        const float* __restrict__ bn_gamma, const float* __restrict__ bn_beta,
        float* __restrict__ cn, float* __restrict__ stats)
{
    const int d = blockIdx.x & 15;
    const int o = (blockIdx.x >> 4) & 7;
    const int b = blockIdx.x >> 7;
    const int px0 = threadIdx.x * 4;

    const float nbn = 1.f / (float)(BATCH * DOUT * HW);
    const float mu = stats[ST_BNSUM + o] * nbn;
    const float var = fmaxf(stats[ST_BNSQ + o] * nbn - mu * mu, 0.f);
    const float rstd = rsqrtf(var + EPSF);
    const float gam = bn_gamma[0], bet = bn_beta[0];

    const size_t gbase = (((size_t)b * CO + o) * DOUT + d) * HW + px0;
    float4 g4 = *reinterpret_cast<const float4*>(&g[gbase]);
    float4 f4;
    f4.x = 1.f + 1.f / (1.f + expf(-((g4.x - mu) * rstd * gam + bet)));
    f4.y = 1.f + 1.f / (1.f + expf(-((g4.y - mu) * rstd * gam + bet)));
    f4.z = 1.f + 1.f / (1.f + expf(-((g4.z - mu) * rstd * gam + bet)));
    f4.w = 1.f + 1.f / (1.f + expf(-((g4.w - mu) * rstd * gam + bet)));

    const float* vpb = votes + ((size_t)b * OC + (size_t)o * DOUT + d) * HW + px0;
    float4 vc[CI];
    #pragma unroll
    for (int c = 0; c < CI; c++)
        vc[c] = *reinterpret_cast<const float4*>(vpb + (size_t)c * (CO * DOUT * HW));

    const float* wv = Wv + (size_t)o * (KCAP * CI) * CI;
    const float* bvo = bv + (size_t)o * (KCAP * CI);

    // softmax(-log std) == (1/std)/sum(1/std); gate factor (1+s) cancels in
    // the softmax and is applied once at the end. v2 floored -> one-hot limit.
    float4 wsum = make_float4(0.f, 0.f, 0.f, 0.f);
    float4 accm = make_float4(0.f, 0.f, 0.f, 0.f);
    #pragma unroll
    for (int ci = 0; ci < CI; ci++) {
        float4 t0v, t1v, t2v, t3v;
        #define EINSUM_KC(TV, KC) do { \
            const int m_ = (KC) * CI + ci; \
            float bm_ = bvo[m_]; \
            TV = make_float4(bm_, bm_, bm_, bm_); \
            _Pragma("unroll") \
            for (int c = 0; c < CI; c++) { \
                float w_ = wv[m_ * CI + c]; \
                TV.x += w_ * vc[c].x; TV.y += w_ * vc[c].y; \
                TV.z += w_ * vc[c].z; TV.w += w_ * vc[c].w; \
            } } while (0)
        EINSUM_KC(t0v, 0); EINSUM_KC(t1v, 1); EINSUM_KC(t2v, 2); EINSUM_KC(t3v, 3);
        #undef EINSUM_KC
        #define ROUTE_COMP(C) do { \
            float s1 = t0v.C + t1v.C + t2v.C + t3v.C; \
            float s2 = t0v.C * t0v.C + t1v.C * t1v.C + t2v.C * t2v.C + t3v.C * t3v.C; \
            float mean_ = s1 * 0.25f; \
            float v2_ = fmaxf(s2 * 0.25f - mean_ * mean_, 1e-30f); \
            float r_ = rsqrtf(v2_); \
            wsum.C += r_; accm.C += r_ * mean_; \
        } while (0)
        ROUTE_COMP(x); ROUTE_COMP(y); ROUTE_COMP(z); ROUTE_COMP(w);
        #undef ROUTE_COMP
    }
    float4 cnv;
    cnv.x = f4.x * accm.x / wsum.x;
    cnv.y = f4.y * accm.y / wsum.y;
    cnv.z = f4.z * accm.z / wsum.z;
    cnv.w = f4.w * accm.w / wsum.w;
    *reinterpret_cast<float4*>(&cn[gbase]) = cnv;

    float s = cnv.x + cnv.y + cnv.z + cnv.w;
    float sq = cnv.x * cnv.x + cnv.y * cnv.y + cnv.z * cnv.z + cnv.w * cnv.w;
    wave_reduce_atomic2(s, sq, &stats[ST_LNSUM + b * CO + o], &stats[ST_LNSQ + b * CO + o]);
}

// ---------------- Kernel D: LayerNorm + transpose-out ------------------------
__global__ __launch_bounds__(256) void ln_kernel(
        const float* __restrict__ cn, const float* __restrict__ stats,
        const float* __restrict__ lng, const float* __restrict__ lnb,
        float* __restrict__ out)
{
    const int bo = blockIdx.x;
    const int b = bo >> 3, o = bo & 7;
    const float nln = 1.f / 16384.f;
    const float mu = stats[ST_LNSUM + bo] * nln;
    const float var = fmaxf(stats[ST_LNSQ + bo] * nln - mu * mu, 0.f);
    const float rstd = rsqrtf(var + EPSF);
    const float* src = cn + (size_t)bo * 16384;
    float* dst = out + ((size_t)o * BATCH + b) * 16384;
    #pragma unroll
    for (int i = 0; i < 16; i++) {
        const int e = i * 1024 + threadIdx.x * 4;
        float4 x = *reinterpret_cast<const float4*>(src + e);
        float4 gm = *reinterpret_cast<const float4*>(lng + e);
        float4 bb = *reinterpret_cast<const float4*>(lnb + e);
        float4 y;
        y.x = (x.x - mu) * rstd * gm.x + bb.x;
        y.y = (x.y - mu) * rstd * gm.y + bb.y;
        y.z = (x.z - mu) * rstd * gm.z + bb.z;
        y.w = (x.w - mu) * rstd * gm.w + bb.w;
        *reinterpret_cast<float4*>(dst + e) = y;
    }
}

extern "C" void kernel_launch(void* const* d_in, const int* in_sizes, int n_in,
                              void* d_out, int out_size, void* d_ws, size_t ws_size,
                              hipStream_t stream) {
    const float* caps = (const float*)d_in[0];
    const float* Wt   = (const float*)d_in[1];
    const float* bt   = (const float*)d_in[2];
    const float* Wv   = (const float*)d_in[3];
    const float* bv   = (const float*)d_in[4];
    const float* Wsp  = (const float*)d_in[5];
    const float* bng  = (const float*)d_in[6];
    const float* bnb  = (const float*)d_in[7];
    const float* lng  = (const float*)d_in[8];
    const float* lnb  = (const float*)d_in[9];
    float* ws = (float*)d_ws;
    float* votes = ws + OFF_VOTES;
    float* g     = ws + OFF_G;
    float* cn    = ws + OFF_CN;
    float* stats = ws + OFF_STATS;
    float* out = (float*)d_out;

    hipMemsetAsync(stats, 0, STATS_FLOATS * sizeof(float), stream);
    conv2d_kernel<<<dim3(32, 32), 256, 0, stream>>>(caps, Wt, bt, votes);
    poolgate_kernel<<<1024, 256, 0, stream>>>(votes, Wv, bv, Wsp, g, stats);
    route_kernel<<<4096, 256, 0, stream>>>(votes, g, Wv, bv, bng, bnb, cn, stats);
    ln_kernel<<<256, 256, 0, stream>>>(cn, stats, lng, lnb, out);
}